// Round 5
// baseline (762.673 us; speedup 1.0000x reference)
//
#include <hip/hip_runtime.h>
#include <math.h>

#define G_   8
#define NPG_ 4096
#define HC_  16
#define LAT_ 64
#define FF_  512
#define EDIM_ 3
#define EH_  64
#define NN_  32768
#define EE_  393216

// ---------------- front-end ----------------
__global__ void k_front1(const float* __restrict__ x, const float* __restrict__ w,
                         const float* __restrict__ b, float* __restrict__ h1) {
  int c = blockIdx.x * blockDim.x + threadIdx.x;
  if (c >= FF_) return;
  float acc[G_];
#pragma unroll
  for (int g = 0; g < G_; g++) acc[g] = 0.f;
  for (int r = 0; r < LAT_; r++) {
    float wv = w[r * FF_ + c];
#pragma unroll
    for (int g = 0; g < G_; g++) acc[g] = fmaf(x[g * LAT_ + r], wv, acc[g]);
  }
#pragma unroll
  for (int g = 0; g < G_; g++) h1[g * FF_ + c] = acc[g] + b[c];
}

__global__ __launch_bounds__(512) void k_front2(const float* __restrict__ h1,
                                                const float* __restrict__ w,
                                                const float* __restrict__ b,
                                                float* __restrict__ hn) {
  __shared__ float sh[G_ * FF_];
  for (int i = threadIdx.x; i < G_ * FF_; i += blockDim.x) sh[i] = h1[i];
  __syncthreads();
  int g = threadIdx.x >> 6;
  int lane = threadIdx.x & 63;
  int c = blockIdx.x * 64 + lane;
  const float* shg = &sh[g * FF_];
  float acc = 0.f;
#pragma unroll 8
  for (int r = 0; r < FF_; r++) acc = fmaf(shg[r], w[r * (NPG_ * HC_) + c], acc);
  float v = acc + b[c];
  hn[g * (NPG_ * HC_) + c] = v > 0.f ? v : expm1f(v);
}

// ---------------- counting sorts ----------------
__global__ void k_zero(int* __restrict__ p, int nv) {
  int i = blockIdx.x * blockDim.x + threadIdx.x;
  if (i < nv) p[i] = 0;
}
__global__ void k_hist(const int* __restrict__ key, int* __restrict__ cnt) {
  int e = blockIdx.x * blockDim.x + threadIdx.x;
  if (e < EE_) atomicAdd(&cnt[key[e]], 1);
}
__global__ __launch_bounds__(1024) void k_scan(const int* __restrict__ cnt,
                                               int* __restrict__ rowptr,
                                               int* __restrict__ cursor) {
  __shared__ int part[1024];
  int t = threadIdx.x;
  int base = t * 32;
  int loc[32];
  int s = 0;
#pragma unroll
  for (int i = 0; i < 32; i++) { loc[i] = s; s += cnt[base + i]; }
  part[t] = s;
  __syncthreads();
  for (int off = 1; off < 1024; off <<= 1) {
    int v = (t >= off) ? part[t - off] : 0;
    __syncthreads();
    part[t] += v;
    __syncthreads();
  }
  int pre = (t == 0) ? 0 : part[t - 1];
#pragma unroll
  for (int i = 0; i < 32; i++) {
    int v = pre + loc[i];
    rowptr[base + i] = v;
    cursor[base + i] = v;
  }
  if (t == 1023) rowptr[NN_] = part[1023];
}
__global__ void k_scatter(const int* __restrict__ src, int* __restrict__ cursor,
                          int* __restrict__ perm) {
  int e = blockIdx.x * blockDim.x + threadIdx.x;
  if (e < EE_) {
    int pos = atomicAdd(&cursor[src[e]], 1);
    perm[pos] = e;
  }
}

// Gather edge data into src-sorted order (ONCE, reused by both convs):
// eas4[k] = (ea0, ea1, ea2, bits(dpos)) of edge perm[k], where dpos is the
// edge's slot in dst-sorted order. Zero padding past E.
__global__ void k_gather(const int* __restrict__ perm, const int* __restrict__ dst,
                         const float* __restrict__ ea, int* __restrict__ cursor_d,
                         float4* __restrict__ eas4) {
  int e = blockIdx.x * blockDim.x + threadIdx.x;
  if (e >= EE_ + 8) return;
  float4 v = make_float4(0.f, 0.f, 0.f, __int_as_float(0));
  if (e < EE_) {
    int eid = perm[e];
    int d = dst[eid];
    int pos = atomicAdd(&cursor_d[d], 1);
    v.x = ea[eid * 3];
    v.y = ea[eid * 3 + 1];
    v.z = ea[eid * 3 + 2];
    v.w = __int_as_float(pos);
  }
  eas4[e] = v;
}

// ---------------- per-conv kernels ----------------
// w2t[o*1024 + i*64 + h] = w2[h*256 + i*16 + o];  w1p4[h] = (w1[0..2][h], b1[h])
__global__ void k_wprep(const float* __restrict__ w2, const float* __restrict__ w1,
                        const float* __restrict__ b1, float* __restrict__ w2t,
                        float4* __restrict__ w1p4) {
  int idx = blockIdx.x * 256 + threadIdx.x;
  if (idx < 16384) {
    int o = idx >> 10, i = (idx >> 6) & 15, h = idx & 63;
    w2t[idx] = w2[h * 256 + i * 16 + o];
  }
  if (idx < 64) {
    w1p4[idx] = make_float4(w1[idx], w1[64 + idx], w1[128 + idx], b1[idx]);
  }
}

// Phase A: per-edge messages, written to dst-sorted slots. One wave per src
// node, no LDS, no atomics. Lane l: o=l&15, q=l>>4; holds M[h=q*16+j][o].
__global__ __launch_bounds__(256, 4) void k_edge(
    const float* __restrict__ hn, const int* __restrict__ rowptr,
    const float4* __restrict__ eas4, const float4* __restrict__ w1p4,
    const float* __restrict__ w2t, const float* __restrict__ b2,
    float* __restrict__ msg) {
  int tid = threadIdx.x;
  int wave = tid >> 6, l = tid & 63;
  int o = l & 15, q = l >> 4;
  int n = blockIdx.x * 4 + wave;

  int rs = rowptr[n], re = rowptr[n + 1];
  if (rs >= re) return;

  float xv[16];
#pragma unroll
  for (int i = 0; i < 16; i++) xv[i] = hn[n * 16 + i];

  float M[16];
#pragma unroll
  for (int j = 0; j < 16; j++) M[j] = 0.f;
  float T = 0.f;
  const float4* __restrict__ w2tv = (const float4*)w2t;
  int base4 = o * 256 + q * 4;
#pragma unroll
  for (int i = 0; i < 16; i++) {
    float xi = xv[i];
    T = fmaf(xi, b2[i * 16 + o], T);
#pragma unroll
    for (int j4 = 0; j4 < 4; j4++) {
      float4 v = w2tv[base4 + i * 16 + j4];
      M[j4 * 4 + 0] = fmaf(xi, v.x, M[j4 * 4 + 0]);
      M[j4 * 4 + 1] = fmaf(xi, v.y, M[j4 * 4 + 1]);
      M[j4 * 4 + 2] = fmaf(xi, v.z, M[j4 * 4 + 2]);
      M[j4 * 4 + 3] = fmaf(xi, v.w, M[j4 * 4 + 3]);
    }
  }

  const float4* __restrict__ w1v = &w1p4[q * 16];

  float4 c0 = eas4[rs], c1 = eas4[rs + 1], c2 = eas4[rs + 2], c3 = eas4[rs + 3];
  for (int k = rs; k < re; k += 4) {
    float4 n0 = eas4[k + 4], n1 = eas4[k + 5], n2 = eas4[k + 6], n3 = eas4[k + 7];

    float p0 = 0.f, p1 = 0.f, p2 = 0.f, p3 = 0.f;
#pragma unroll
    for (int j = 0; j < 16; j++) {
      float4 wv = w1v[j];
      float m = M[j];
      float h0 = fmaxf(fmaf(c0.z, wv.z, fmaf(c0.y, wv.y, fmaf(c0.x, wv.x, wv.w))), 0.f);
      float h1 = fmaxf(fmaf(c1.z, wv.z, fmaf(c1.y, wv.y, fmaf(c1.x, wv.x, wv.w))), 0.f);
      float h2 = fmaxf(fmaf(c2.z, wv.z, fmaf(c2.y, wv.y, fmaf(c2.x, wv.x, wv.w))), 0.f);
      float h3 = fmaxf(fmaf(c3.z, wv.z, fmaf(c3.y, wv.y, fmaf(c3.x, wv.x, wv.w))), 0.f);
      p0 = fmaf(h0, m, p0);
      p1 = fmaf(h1, m, p1);
      p2 = fmaf(h2, m, p2);
      p3 = fmaf(h3, m, p3);
    }
    // butterfly: afterwards every lane holds the full 64-lane sum of each p
    p0 += __shfl_xor(p0, 16); p1 += __shfl_xor(p1, 16);
    p2 += __shfl_xor(p2, 16); p3 += __shfl_xor(p3, 16);
    p0 += __shfl_xor(p0, 32); p1 += __shfl_xor(p1, 32);
    p2 += __shfl_xor(p2, 32); p3 += __shfl_xor(p3, 32);

    // lane group q stores edge k+q's message (16 floats, one 64B line)
    float vv = (q == 0) ? p0 : (q == 1) ? p1 : (q == 2) ? p2 : p3;
    float dpf = (q == 0) ? c0.w : (q == 1) ? c1.w : (q == 2) ? c2.w : c3.w;
    if (k + q < re) msg[__float_as_int(dpf) * 16 + o] = vv + T;

    c0 = n0; c1 = n1; c2 = n2; c3 = n3;
  }
}

// Phase B: one wave per dst node. Sum dst-sorted messages + root matvec,
// bias, ELU, write final node features (fuses nodeinit+elu).
__global__ __launch_bounds__(256) void k_post(
    const float* __restrict__ hn, const float* __restrict__ msg,
    const int* __restrict__ rowptrD, const float* __restrict__ root,
    const float* __restrict__ bias, float* __restrict__ outp) {
  int tid = threadIdx.x;
  int wave = tid >> 6, l = tid & 63;
  int o = l & 15, q = l >> 4;
  int d = blockIdx.x * 4 + wave;

  int rs = rowptrD[d], re = rowptrD[d + 1];

  float acc = 0.f;
#pragma unroll
  for (int t = 0; t < 4; t++)
    acc = fmaf(hn[d * 16 + q * 4 + t], root[(q * 4 + t) * 16 + o], acc);
  for (int k = rs + q; k < re; k += 4) acc += msg[k * 16 + o];

  acc += __shfl_xor(acc, 16);
  acc += __shfl_xor(acc, 32);
  if (l < 16) {
    float v = acc + bias[o];
    outp[d * 16 + o] = v > 0.f ? v : expm1f(v);
  }
}

// ---------------- launch ----------------
extern "C" void kernel_launch(void* const* d_in, const int* in_sizes, int n_in,
                              void* d_out, int out_size, void* d_ws, size_t ws_size,
                              hipStream_t stream) {
  const float* x    = (const float*)d_in[0];
  const int*   ei   = (const int*)d_in[1];
  const float* ea   = (const float*)d_in[2];
  const float* fc2w = (const float*)d_in[3];
  const float* fc2b = (const float*)d_in[4];
  const float* fc1w = (const float*)d_in[5];
  const float* fc1b = (const float*)d_in[6];
  float* out = (float*)d_out;

  float* ws = (float*)d_ws;
  // float-offset layout (16B alignment kept for float4 arrays)
  float*  h1      = ws;                        // @0        4096
  float*  hnode   = ws + 4096;                 // @4096     524288
  float*  w2t     = ws + 528384;               // 16384
  float4* w1p4    = (float4*)(ws + 544768);    // 256 floats
  float4* eas4    = (float4*)(ws + 545024);    // (E+8)*4 = 1572896 floats
  float*  msg     = ws + 2117920;              // (E+8)*16 = 6291584 floats
  int*    cnt     = (int*)(ws + 8409504);      // N
  int*    rowptr  = cnt + NN_;                 // N+1
  int*    cursor  = rowptr + NN_ + 1;          // N
  int*    cnt_d   = cursor + NN_;              // N
  int*    rowptrD = cnt_d + NN_;               // N+1
  int*    cursor_d= rowptrD + NN_ + 1;         // N
  int*    perm    = cursor_d + NN_;            // E

  const int* src  = ei;
  const int* dstp = ei + EE_;

  k_front1<<<2, 256, 0, stream>>>(x, fc2w, fc2b, h1);
  k_front2<<<1024, 512, 0, stream>>>(h1, fc1w, fc1b, hnode);

  // src sort
  k_zero<<<(NN_ + 255) / 256, 256, 0, stream>>>(cnt, NN_);
  k_hist<<<(EE_ + 255) / 256, 256, 0, stream>>>(src, cnt);
  k_scan<<<1, 1024, 0, stream>>>(cnt, rowptr, cursor);
  k_scatter<<<(EE_ + 255) / 256, 256, 0, stream>>>(src, cursor, perm);
  // dst sort (rowptr + cursors only)
  k_zero<<<(NN_ + 255) / 256, 256, 0, stream>>>(cnt_d, NN_);
  k_hist<<<(EE_ + 255) / 256, 256, 0, stream>>>(dstp, cnt_d);
  k_scan<<<1, 1024, 0, stream>>>(cnt_d, rowptrD, cursor_d);
  // gather edge attrs + dst-slot assignment
  k_gather<<<(EE_ + 8 + 255) / 256, 256, 0, stream>>>(perm, dstp, ea, cursor_d, eas4);

  for (int cv = 0; cv < 2; cv++) {
    const float* root = (const float*)d_in[7 + cv * 6];
    const float* cb   = (const float*)d_in[8 + cv * 6];
    const float* w1   = (const float*)d_in[9 + cv * 6];
    const float* b1   = (const float*)d_in[10 + cv * 6];
    const float* w2   = (const float*)d_in[11 + cv * 6];
    const float* b2   = (const float*)d_in[12 + cv * 6];
    k_wprep<<<64, 256, 0, stream>>>(w2, w1, b1, w2t, w1p4);
    k_edge<<<NN_ / 4, 256, 0, stream>>>(hnode, rowptr, eas4, w1p4, w2t, b2, msg);
    k_post<<<NN_ / 4, 256, 0, stream>>>(hnode, msg, rowptrD, root, cb,
                                        cv == 0 ? hnode : out);
  }
}